// Round 1
// 1885.754 us; speedup vs baseline: 1.2394x; 1.2394x over previous
//
#include <hip/hip_runtime.h>
#include <stdint.h>

#define NF 51
#define UNITS 128
#define G3 384
#define OUT_C 102
#define NW 13158            // UNITS*OUT_C + OUT_C
#define GAMMA 28
#define KW_ELEMS 368424     // GAMMA * NW
#define BATCH 8192
#define SEQ_T 64
#define TSTEPS 50           // 64 - LAG(14)
#define NDEC 27
#define BR 32               // batch rows per block
#define THREADS 1024        // 16 waves
#define CCONST 0.5413248546129181f
#define WF_USHORTS 147456   // 24 nb * 6 ks * 2 split * 64 lanes * 8 elems

typedef __attribute__((ext_vector_type(8))) short bf16x8;
typedef __attribute__((ext_vector_type(4))) float f32x4;
typedef unsigned short ushort_t;

// ---------- JAX threefry2x32 (20 rounds), host+device ----------
__host__ __device__ __forceinline__ void tf2x32(uint32_t k0, uint32_t k1,
    uint32_t x0, uint32_t x1, uint32_t& o0, uint32_t& o1)
{
  uint32_t ks2 = k0 ^ k1 ^ 0x1BD11BDAu;
  x0 += k0; x1 += k1;
#define TF_R(r) { x0 += x1; x1 = (x1 << (r)) | (x1 >> (32 - (r))); x1 ^= x0; }
  TF_R(13) TF_R(15) TF_R(26) TF_R(6)  x0 += k1;  x1 += ks2 + 1u;
  TF_R(17) TF_R(29) TF_R(16) TF_R(24) x0 += ks2; x1 += k0 + 2u;
  TF_R(13) TF_R(15) TF_R(26) TF_R(6)  x0 += k0;  x1 += k1 + 3u;
  TF_R(17) TF_R(29) TF_R(16) TF_R(24) x0 += k1;  x1 += ks2 + 4u;
  TF_R(13) TF_R(15) TF_R(26) TF_R(6)  x0 += ks2; x1 += k0 + 5u;
#undef TF_R
  o0 = x0; o1 = x1;
}

// XLA ErfInv32 (Giles)
__device__ __forceinline__ float erfinv_f(float x) {
  float w = -log1pf(-x * x);
  float p;
  if (w < 5.0f) {
    w -= 2.5f;
    p = 2.81022636e-08f;
    p = fmaf(p, w, 3.43273939e-07f);
    p = fmaf(p, w, -3.5233877e-06f);
    p = fmaf(p, w, -4.39150654e-06f);
    p = fmaf(p, w, 0.00021858087f);
    p = fmaf(p, w, -0.00125372503f);
    p = fmaf(p, w, -0.00417768164f);
    p = fmaf(p, w, 0.246640727f);
    p = fmaf(p, w, 1.50140941f);
  } else {
    w = sqrtf(w) - 3.0f;
    p = -0.000200214257f;
    p = fmaf(p, w, 0.000100950558f);
    p = fmaf(p, w, 0.00134934322f);
    p = fmaf(p, w, -0.00367342844f);
    p = fmaf(p, w, 0.00573950773f);
    p = fmaf(p, w, -0.0076224613f);
    p = fmaf(p, w, 0.00943887047f);
    p = fmaf(p, w, 1.00167406f);
    p = fmaf(p, w, 2.83297682f);
  }
  return p * x;
}

__device__ __forceinline__ float jax_normal(uint32_t k0, uint32_t k1, uint32_t i)
{
  uint32_t y0, y1;
  tf2x32(k0, k1, 0u, i, y0, y1);
  uint32_t bits = y0 ^ y1;
  uint32_t fb = (bits >> 9) | 0x3f800000u;
  float f = __uint_as_float(fb) - 1.0f;       // [0,1)
  const float lo = -0.99999994f;
  const float d  = 1.99999994f;
  float u = __fadd_rn(__fmul_rn(f, d), lo);   // XLA uses mul+add (no fma)
  u = fmaxf(lo, u);
  return 1.41421354f * erfinv_f(u);
}

__device__ __forceinline__ float softplus_f(float x) {
  return fmaxf(x, 0.0f) + log1pf(expf(-fabsf(x)));
}
__device__ __forceinline__ float sigmoid_f(float x) {
  return 1.0f / (1.0f + expf(-x));
}

// f32 <-> bf16 bits (RNE); values are well-behaved (no NaN handling needed)
__device__ __forceinline__ ushort_t f2bf(float f) {
  uint32_t u = __float_as_uint(f);
  uint32_t r = (u + 0x7fffu + ((u >> 16) & 1u)) >> 16;
  return (ushort_t)r;
}
__device__ __forceinline__ float bf2f(ushort_t h) {
  return __uint_as_float(((uint32_t)h) << 16);
}

// ---------- prep kernel 1: sample the 28 decoder weight sets ----------
__global__ void sample_w_kernel(const float* __restrict__ post_loc,
                                const float* __restrict__ post_rho,
                                float* __restrict__ wout,
                                uint32_t kw0, uint32_t kw1)
{
  int i = blockIdx.x * 256 + threadIdx.x;
  if (i >= KW_ELEMS) return;
  int widx = i % NW;
  float eps = jax_normal(kw0, kw1, (uint32_t)i);
  float sc = 1e-5f + 0.02f * softplus_f(CCONST + post_rho[widx]);
  wout[i] = fmaf(sc, eps, post_loc[widx]);
}

// ---------- prep kernel 2: build MFMA B-fragment-ordered split-bf16 weights ----
// Layout: WF[nb(24)][ks(6)][split(2)][lane(64)][elem(8)] ushorts.
// nb = 16-col tile of the 384 gate columns. ks 0..3 = Wh rows 32ks..32ks+31,
// ks 4..5 = Wx rows 32(ks-4).. (rows >= NF zero-padded).
// Fragment: lane L holds B[k = 8*(L>>4)+elem][col = 16*nb + (L&15)].
__global__ void build_wf_kernel(const float* __restrict__ Wh,   // (128,384)
                                const float* __restrict__ Wx,   // (51,384)
                                ushort_t* __restrict__ wf)
{
  int t = blockIdx.x * 256 + threadIdx.x;
  if (t >= WF_USHORTS) return;
  int e    = t & 7;
  int lane = (t >> 3) & 63;
  int sp   = (t >> 9) & 1;
  int q    = t >> 10;          // nb*6 + ks
  int ks   = q % 6;
  int nb   = q / 6;
  int kl   = 8 * (lane >> 4) + e;
  int col  = 16 * nb + (lane & 15);
  float w;
  if (ks < 4) {
    w = Wh[(32 * ks + kl) * G3 + col];
  } else {
    int row = 32 * (ks - 4) + kl;
    w = (row < NF) ? Wx[row * G3 + col] : 0.0f;
  }
  ushort_t hi = f2bf(w);
  wf[t] = (sp == 0) ? hi : f2bf(w - bf2f(hi));
}

// ---------- main kernel ----------
// GRU matmuls on matrix cores via split-bf16 (hi/lo, 3 mfma per product).
// Per step: C[32x384] gate pre-acts; nb<16 -> z/r (h- and x-GEMM fused into
// one acc chain), nb>=16 -> h-gate with separate rh (ks<4) / xh (ks>=4) accs.
// Wave w handles nb = {w, w+16} (w<8) or {w} (w>=8); both 16-row m-tiles per
// wave so each B-fragment is loaded once per step per CU pair of m-tiles.
__global__ __launch_bounds__(THREADS, 4) void irnn_main(
    const float* __restrict__ x,      // (8192, 64, 51)
    const float* __restrict__ gbias,  // (2, 384)
    const float* __restrict__ Wdec,   // (28, 13158) sampled
    const ushort_t* __restrict__ WF,  // fragment weights
    float* __restrict__ out,          // (8192, 28, 102)
    uint32_t ks0, uint32_t ks1)
{
  __shared__ float m_zr[BR][260];                    // cols 0..255 (pad->2-way free)
  __shared__ float m_rh[BR][132];                    // recurrent h-gate part
  __shared__ float m_xh[BR][132];                    // input h-gate part
  __shared__ float h_f32[BR][UNITS];                 // for f32 head GEMM
  __shared__ __align__(16) ushort_t h_hi[BR][136];   // bf16 hi, pad 128->136
  __shared__ __align__(16) ushort_t h_lo[BR][136];
  __shared__ __align__(16) ushort_t s_hi[BR][72];    // K-pad 52..63 zero
  __shared__ __align__(16) ushort_t s_lo[BR][72];
  __shared__ float t_lds[BR][OUT_C];

  const int tid  = threadIdx.x;
  const int b0   = blockIdx.x * BR;
  const int lane = tid & 63;
  const int wv   = tid >> 6;          // 0..15
  const int kg   = lane >> 4;         // k-group 0..3
  const int fr   = lane & 15;         // frag row (A) / col (B,D)

  // combine-phase mapping: u = tid&127, 4 rows per thread
  const int cu  = tid & 127;
  const int rb4 = (tid >> 7) * 4;
  const float bz  = gbias[cu]           + gbias[G3 + cu];
  const float brg = gbias[UNITS + cu]   + gbias[G3 + UNITS + cu];
  const float bxh = gbias[2*UNITS + cu];
  const float brh = gbias[G3 + 2*UNITS + cu];

  float hreg[4] = {0.f, 0.f, 0.f, 0.f};

  for (int i = tid; i < BR * 136; i += THREADS) { (&h_hi[0][0])[i] = 0; (&h_lo[0][0])[i] = 0; }
  for (int i = tid; i < BR * 72;  i += THREADS) { (&s_hi[0][0])[i] = 0; (&s_lo[0][0])[i] = 0; }
  for (int i = tid; i < BR * UNITS; i += THREADS) (&h_f32[0][0])[i] = 0.f;
  __syncthreads();

  // ---- MFMA GEMM phase: fills m_zr / m_rh / m_xh ----
  auto gemm_phase = [&]() {
    for (int nb = wv; nb < 24; nb += 16) {
      const ushort_t* wfb = WF + (size_t)nb * 6144 + lane * 8;
      f32x4 acc0m0 = {0,0,0,0}, acc0m1 = {0,0,0,0};   // z/r (or rh for nb>=16)
      f32x4 acc1m0 = {0,0,0,0}, acc1m1 = {0,0,0,0};   // xh (nb>=16 only)
      #pragma unroll
      for (int ks = 0; ks < 6; ++ks) {
        bf16x8 bh = *(const bf16x8*)(wfb + (2*ks + 0) * 512);
        bf16x8 bl = *(const bf16x8*)(wfb + (2*ks + 1) * 512);
        bf16x8 a0h, a0l, a1h, a1l;
        if (ks < 4) {
          const int off = 32*ks + 8*kg;
          a0h = *(const bf16x8*)&h_hi[fr][off];
          a0l = *(const bf16x8*)&h_lo[fr][off];
          a1h = *(const bf16x8*)&h_hi[16 + fr][off];
          a1l = *(const bf16x8*)&h_lo[16 + fr][off];
        } else {
          const int off = 32*(ks-4) + 8*kg;
          a0h = *(const bf16x8*)&s_hi[fr][off];
          a0l = *(const bf16x8*)&s_lo[fr][off];
          a1h = *(const bf16x8*)&s_hi[16 + fr][off];
          a1l = *(const bf16x8*)&s_lo[16 + fr][off];
        }
        if (nb < 16 || ks < 4) {
          acc0m0 = __builtin_amdgcn_mfma_f32_16x16x32_bf16(a0h, bh, acc0m0, 0,0,0);
          acc0m0 = __builtin_amdgcn_mfma_f32_16x16x32_bf16(a0h, bl, acc0m0, 0,0,0);
          acc0m0 = __builtin_amdgcn_mfma_f32_16x16x32_bf16(a0l, bh, acc0m0, 0,0,0);
          acc0m1 = __builtin_amdgcn_mfma_f32_16x16x32_bf16(a1h, bh, acc0m1, 0,0,0);
          acc0m1 = __builtin_amdgcn_mfma_f32_16x16x32_bf16(a1h, bl, acc0m1, 0,0,0);
          acc0m1 = __builtin_amdgcn_mfma_f32_16x16x32_bf16(a1l, bh, acc0m1, 0,0,0);
        } else {
          acc1m0 = __builtin_amdgcn_mfma_f32_16x16x32_bf16(a0h, bh, acc1m0, 0,0,0);
          acc1m0 = __builtin_amdgcn_mfma_f32_16x16x32_bf16(a0h, bl, acc1m0, 0,0,0);
          acc1m0 = __builtin_amdgcn_mfma_f32_16x16x32_bf16(a0l, bh, acc1m0, 0,0,0);
          acc1m1 = __builtin_amdgcn_mfma_f32_16x16x32_bf16(a1h, bh, acc1m1, 0,0,0);
          acc1m1 = __builtin_amdgcn_mfma_f32_16x16x32_bf16(a1h, bl, acc1m1, 0,0,0);
          acc1m1 = __builtin_amdgcn_mfma_f32_16x16x32_bf16(a1l, bh, acc1m1, 0,0,0);
        }
      }
      // D layout: col = lane&15, row = 4*(lane>>4)+j  [verified m89/m91]
      const int orow = 4 * kg;
      if (nb < 16) {
        const int c = 16*nb + fr;
        #pragma unroll
        for (int j = 0; j < 4; ++j) {
          m_zr[orow + j][c]      = acc0m0[j];
          m_zr[16 + orow + j][c] = acc0m1[j];
        }
      } else {
        const int c = 16*(nb - 16) + fr;
        #pragma unroll
        for (int j = 0; j < 4; ++j) {
          m_rh[orow + j][c]      = acc0m0[j];
          m_xh[orow + j][c]      = acc1m0[j];
          m_rh[16 + orow + j][c] = acc0m1[j];
          m_xh[16 + orow + j][c] = acc1m1[j];
        }
      }
    }
  };

  // ---- gate elementwise + h update + bf16 split ----
  auto combine = [&]() {
    #pragma unroll
    for (int j = 0; j < 4; ++j) {
      const int r = rb4 + j;
      float az = m_zr[r][cu]         + bz;
      float ar = m_zr[r][UNITS + cu] + brg;
      float rh = m_rh[r][cu]         + brh;
      float xh = m_xh[r][cu]         + bxh;
      float z  = sigmoid_f(az);
      float rr = sigmoid_f(ar);
      float hh = tanhf(fmaf(rr, rh, xh));
      float h  = z * hreg[j] + (1.0f - z) * hh;
      hreg[j]  = h;
      h_f32[r][cu] = h;
      ushort_t hi = f2bf(h);
      h_hi[r][cu] = hi;
      h_lo[r][cu] = f2bf(h - bf2f(hi));
    }
  };

  // ---- f32 head GEMM (unchanged structure): t = h @ K_g + b_g ----
  const int tc  = tid & 127;
  const int trg = tid >> 7;
  auto tgemm = [&](int g) {
    if (tc < OUT_C) {
      const float* K = Wdec + (size_t)g * NW;
      float acc[4] = {};
      #pragma unroll 2
      for (int kk = 0; kk < UNITS; kk += 4) {
        float kw[4];
        #pragma unroll
        for (int q = 0; q < 4; ++q) kw[q] = K[(kk + q) * OUT_C + tc];
        #pragma unroll
        for (int r = 0; r < 4; ++r) {
          float4 h4 = *(const float4*)&h_f32[trg * 4 + r][kk];
          acc[r] = fmaf(h4.x, kw[0], acc[r]); acc[r] = fmaf(h4.y, kw[1], acc[r]);
          acc[r] = fmaf(h4.z, kw[2], acc[r]); acc[r] = fmaf(h4.w, kw[3], acc[r]);
        }
      }
      float kb = K[UNITS * OUT_C + tc];
      #pragma unroll
      for (int r = 0; r < 4; ++r) {
        float tv = acc[r] + kb;
        t_lds[trg * 4 + r][tc] = tv;
        float ov = (tc < NF) ? tv
                             : (1e-5f + 0.05f * softplus_f(CCONST + tv));
        out[(size_t)(b0 + trg * 4 + r) * (GAMMA * OUT_C) + g * OUT_C + tc] = ov;
      }
    }
  };

  // ---- decoder input: s = loc + scale * eps_s[j] (split to bf16 hi/lo) ----
  auto sphase = [&](int j) {
    for (int idx = tid; idx < BR * NF; idx += THREADS) {
      int r = idx / NF, f = idx - r * NF;
      float loc = t_lds[r][f];
      float sc = 1e-5f + 0.05f * softplus_f(CCONST + t_lds[r][NF + f]);
      uint32_t gi = (uint32_t)((j * BATCH + b0 + r) * NF + f);
      float es = jax_normal(ks0, ks1, gi);
      float s = fmaf(sc, es, loc);
      ushort_t hi = f2bf(s);
      s_hi[r][f] = hi;
      s_lo[r][f] = f2bf(s - bf2f(hi));
    }
  };

  // ---- encoder: 50 steps ----
  for (int t = 0; t < TSTEPS; ++t) {
    for (int idx = tid; idx < BR * NF; idx += THREADS) {
      int r = idx / NF, f = idx - r * NF;
      float v = x[(size_t)(b0 + r) * (SEQ_T * NF) + t * NF + f];
      ushort_t hi = f2bf(v);
      s_hi[r][f] = hi;
      s_lo[r][f] = f2bf(v - bf2f(hi));
    }
    __syncthreads();
    gemm_phase();
    __syncthreads();
    combine();
    __syncthreads();
  }
  tgemm(0);
  __syncthreads();

  // ---- decoder: 27 steps ----
  for (int j = 0; j < NDEC; ++j) {
    sphase(j);
    __syncthreads();
    gemm_phase();
    __syncthreads();
    combine();
    __syncthreads();
    tgemm(j + 1);
    __syncthreads();
  }
}

extern "C" void kernel_launch(void* const* d_in, const int* in_sizes, int n_in,
                              void* d_out, int out_size, void* d_ws, size_t ws_size,
                              hipStream_t stream)
{
  const float* x    = (const float*)d_in[0];
  const float* gk   = (const float*)d_in[1];   // (51, 384)
  const float* grk  = (const float*)d_in[2];   // (128, 384)
  const float* gb   = (const float*)d_in[3];
  const float* ploc = (const float*)d_in[4];
  const float* prho = (const float*)d_in[5];

  float* wdec = (float*)d_ws;                          // 368424 floats (1.47 MB)
  ushort_t* wf = (ushort_t*)(wdec + KW_ELEMS);         // 147456 ushorts (288 KB)

  uint32_t kw0, kw1, ksd0, ksd1;
  tf2x32(0u, 42u, 0u, 0u, kw0, kw1);
  tf2x32(0u, 42u, 0u, 1u, ksd0, ksd1);

  sample_w_kernel<<<(KW_ELEMS + 255) / 256, 256, 0, stream>>>(ploc, prho, wdec, kw0, kw1);
  build_wf_kernel<<<(WF_USHORTS + 255) / 256, 256, 0, stream>>>(grk, gk, wf);
  irnn_main<<<BATCH / BR, THREADS, 0, stream>>>(x, gb, wdec, wf,
                                                (float*)d_out, ksd0, ksd1);
}

// Round 2
// 1148.228 us; speedup vs baseline: 2.0355x; 1.6423x over previous
//
#include <hip/hip_runtime.h>
#include <stdint.h>

#define NF 51
#define UNITS 128
#define G3 384
#define OUT_C 102
#define NW 13158            // UNITS*OUT_C + OUT_C
#define GAMMA 28
#define KW_ELEMS 368424     // GAMMA * NW
#define BATCH 8192
#define SEQ_T 64
#define TSTEPS 50           // 64 - LAG(14)
#define NDEC 27
#define BR 32               // batch rows per block
#define THREADS 1024        // 16 waves
#define CCONST 0.5413248546129181f
#define WF_USHORTS 147456   // 24 nb * 6 ks * 2 split * 64 lanes * 8 elems

typedef __attribute__((ext_vector_type(8))) short bf16x8;
typedef __attribute__((ext_vector_type(4))) float f32x4;
typedef unsigned short ushort_t;

// ---------- JAX threefry2x32 (20 rounds), host+device ----------
__host__ __device__ __forceinline__ void tf2x32(uint32_t k0, uint32_t k1,
    uint32_t x0, uint32_t x1, uint32_t& o0, uint32_t& o1)
{
  uint32_t ks2 = k0 ^ k1 ^ 0x1BD11BDAu;
  x0 += k0; x1 += k1;
#define TF_R(r) { x0 += x1; x1 = (x1 << (r)) | (x1 >> (32 - (r))); x1 ^= x0; }
  TF_R(13) TF_R(15) TF_R(26) TF_R(6)  x0 += k1;  x1 += ks2 + 1u;
  TF_R(17) TF_R(29) TF_R(16) TF_R(24) x0 += ks2; x1 += k0 + 2u;
  TF_R(13) TF_R(15) TF_R(26) TF_R(6)  x0 += k0;  x1 += k1 + 3u;
  TF_R(17) TF_R(29) TF_R(16) TF_R(24) x0 += k1;  x1 += ks2 + 4u;
  TF_R(13) TF_R(15) TF_R(26) TF_R(6)  x0 += ks2; x1 += k0 + 5u;
#undef TF_R
  o0 = x0; o1 = x1;
}

// XLA ErfInv32 (Giles)
__device__ __forceinline__ float erfinv_f(float x) {
  float w = -log1pf(-x * x);
  float p;
  if (w < 5.0f) {
    w -= 2.5f;
    p = 2.81022636e-08f;
    p = fmaf(p, w, 3.43273939e-07f);
    p = fmaf(p, w, -3.5233877e-06f);
    p = fmaf(p, w, -4.39150654e-06f);
    p = fmaf(p, w, 0.00021858087f);
    p = fmaf(p, w, -0.00125372503f);
    p = fmaf(p, w, -0.00417768164f);
    p = fmaf(p, w, 0.246640727f);
    p = fmaf(p, w, 1.50140941f);
  } else {
    w = sqrtf(w) - 3.0f;
    p = -0.000200214257f;
    p = fmaf(p, w, 0.000100950558f);
    p = fmaf(p, w, 0.00134934322f);
    p = fmaf(p, w, -0.00367342844f);
    p = fmaf(p, w, 0.00573950773f);
    p = fmaf(p, w, -0.0076224613f);
    p = fmaf(p, w, 0.00943887047f);
    p = fmaf(p, w, 1.00167406f);
    p = fmaf(p, w, 2.83297682f);
  }
  return p * x;
}

__device__ __forceinline__ float jax_normal(uint32_t k0, uint32_t k1, uint32_t i)
{
  uint32_t y0, y1;
  tf2x32(k0, k1, 0u, i, y0, y1);
  uint32_t bits = y0 ^ y1;
  uint32_t fb = (bits >> 9) | 0x3f800000u;
  float f = __uint_as_float(fb) - 1.0f;       // [0,1)
  const float lo = -0.99999994f;
  const float d  = 1.99999994f;
  float u = __fadd_rn(__fmul_rn(f, d), lo);   // XLA uses mul+add (no fma)
  u = fmaxf(lo, u);
  return 1.41421354f * erfinv_f(u);
}

__device__ __forceinline__ float softplus_f(float x) {
  return fmaxf(x, 0.0f) + log1pf(expf(-fabsf(x)));
}
__device__ __forceinline__ float sigmoid_f(float x) {
  return 1.0f / (1.0f + expf(-x));
}

// f32 <-> bf16 bits (RNE)
__device__ __forceinline__ ushort_t f2bf(float f) {
  uint32_t u = __float_as_uint(f);
  uint32_t r = (u + 0x7fffu + ((u >> 16) & 1u)) >> 16;
  return (ushort_t)r;
}
__device__ __forceinline__ float bf2f(ushort_t h) {
  return __uint_as_float(((uint32_t)h) << 16);
}

// ---------- prep kernel 1: sample the 28 decoder weight sets ----------
__global__ void sample_w_kernel(const float* __restrict__ post_loc,
                                const float* __restrict__ post_rho,
                                float* __restrict__ wout,
                                uint32_t kw0, uint32_t kw1)
{
  int i = blockIdx.x * 256 + threadIdx.x;
  if (i >= KW_ELEMS) return;
  int widx = i % NW;
  float eps = jax_normal(kw0, kw1, (uint32_t)i);
  float sc = 1e-5f + 0.02f * softplus_f(CCONST + post_rho[widx]);
  wout[i] = fmaf(sc, eps, post_loc[widx]);
}

// ---------- prep kernel 2: build MFMA B-fragment-ordered split-bf16 weights ----
// Layout: WF[nb(24)][ks(6)][split(2)][lane(64)][elem(8)] ushorts.
// nb = 16-col tile of the 384 gate columns. ks 0..3 = Wh rows 32ks..32ks+31,
// ks 4..5 = Wx rows 32(ks-4).. (rows >= NF zero-padded).
// Fragment: lane L holds B[k = 8*(L>>4)+elem][col = 16*nb + (L&15)].
__global__ void build_wf_kernel(const float* __restrict__ Wh,   // (128,384)
                                const float* __restrict__ Wx,   // (51,384)
                                ushort_t* __restrict__ wf)
{
  int t = blockIdx.x * 256 + threadIdx.x;
  if (t >= WF_USHORTS) return;
  int e    = t & 7;
  int lane = (t >> 3) & 63;
  int sp   = (t >> 9) & 1;
  int q    = t >> 10;          // nb*6 + ks
  int ks   = q % 6;
  int nb   = q / 6;
  int kl   = 8 * (lane >> 4) + e;
  int col  = 16 * nb + (lane & 15);
  float w;
  if (ks < 4) {
    w = Wh[(32 * ks + kl) * G3 + col];
  } else {
    int row = 32 * (ks - 4) + kl;
    w = (row < NF) ? Wx[row * G3 + col] : 0.0f;
  }
  ushort_t hi = f2bf(w);
  wf[t] = (sp == 0) ? hi : f2bf(w - bf2f(hi));
}

// ---------- main kernel ----------
// 48 output tiles (2 m x 24 n) over 16 waves = exactly 3 tiles/wave:
// wave wv: m = wv&1, g3 = wv>>1 (0..7); tiles nb = {g3 (z), 8+g3 (r), 16+g3 (h)}.
// All 3 tiles share the same m -> A-frags loaded once per ks; B-frags for the
// m-pair (wv^1) de-dup through L1. Live set ~45 VGPRs: no spills.
// amdgpu_waves_per_eu(4,4): block is 16 waves = 4/SIMD regardless (LDS 123KB,
// grid 256 = #CUs), so let the allocator use up to 128 VGPRs.
__global__ __launch_bounds__(THREADS, 4)
__attribute__((amdgpu_waves_per_eu(4, 4)))
void irnn_main(
    const float* __restrict__ x,      // (8192, 64, 51)
    const float* __restrict__ gbias,  // (2, 384)
    const float* __restrict__ Wdec,   // (28, 13158) sampled
    const ushort_t* __restrict__ WF,  // fragment weights
    float* __restrict__ out,          // (8192, 28, 102)
    uint32_t ks0, uint32_t ks1)
{
  __shared__ float m_zr[BR][260];                    // z cols 0..127, r cols 128..255
  __shared__ float m_rh[BR][132];                    // recurrent h-gate part
  __shared__ float m_xh[BR][132];                    // input h-gate part
  __shared__ float h_f32[BR][UNITS];                 // for f32 head GEMM
  __shared__ __align__(16) ushort_t h_hi[BR][136];   // bf16 hi, pad 128->136
  __shared__ __align__(16) ushort_t h_lo[BR][136];
  __shared__ __align__(16) ushort_t s_hi[BR][72];    // K-pad 52..63 zero
  __shared__ __align__(16) ushort_t s_lo[BR][72];
  __shared__ float t_lds[BR][OUT_C];

  const int tid  = threadIdx.x;
  const int b0   = blockIdx.x * BR;
  const int lane = tid & 63;
  const int wv   = tid >> 6;          // 0..15
  const int kg   = lane >> 4;         // k-group 0..3
  const int fr   = lane & 15;         // frag row (A) / col (B,D)
  const int g3   = wv >> 1;           // 0..7 -> n-tile group
  const int mrow = wv & 1;            // m-tile
  const int rbase = 16 * mrow;

  // combine-phase mapping: u = tid&127, 4 rows per thread
  const int cu  = tid & 127;
  const int rb4 = (tid >> 7) * 4;
  const float bz  = gbias[cu]           + gbias[G3 + cu];
  const float brg = gbias[UNITS + cu]   + gbias[G3 + UNITS + cu];
  const float bxh = gbias[2*UNITS + cu];
  const float brh = gbias[G3 + 2*UNITS + cu];

  float hreg[4] = {0.f, 0.f, 0.f, 0.f};

  for (int i = tid; i < BR * 136; i += THREADS) { (&h_hi[0][0])[i] = 0; (&h_lo[0][0])[i] = 0; }
  for (int i = tid; i < BR * 72;  i += THREADS) { (&s_hi[0][0])[i] = 0; (&s_lo[0][0])[i] = 0; }
  for (int i = tid; i < BR * UNITS; i += THREADS) (&h_f32[0][0])[i] = 0.f;
  __syncthreads();

  const ushort_t* wfz = WF + (size_t)g3        * 6144 + (size_t)lane * 8;
  const ushort_t* wfr = WF + (size_t)(8 + g3)  * 6144 + (size_t)lane * 8;
  const ushort_t* wfh = WF + (size_t)(16 + g3) * 6144 + (size_t)lane * 8;

  // ---- MFMA GEMM phase: fills m_zr / m_rh / m_xh ----
  auto gemm_phase = [&]() {
    f32x4 acc_z  = {0.f,0.f,0.f,0.f};
    f32x4 acc_r  = {0.f,0.f,0.f,0.f};
    f32x4 acc_rh = {0.f,0.f,0.f,0.f};
    f32x4 acc_xh = {0.f,0.f,0.f,0.f};
    // ks 0..3: A from h (recurrent part)
    #pragma unroll 2
    for (int ks = 0; ks < 4; ++ks) {
      const int off = 32*ks + 8*kg;
      bf16x8 ah = *(const bf16x8*)&h_hi[rbase + fr][off];
      bf16x8 al = *(const bf16x8*)&h_lo[rbase + fr][off];
      bf16x8 bh = *(const bf16x8*)(wfz + (2*ks + 0) * 512);
      bf16x8 bl = *(const bf16x8*)(wfz + (2*ks + 1) * 512);
      acc_z = __builtin_amdgcn_mfma_f32_16x16x32_bf16(ah, bh, acc_z, 0,0,0);
      acc_z = __builtin_amdgcn_mfma_f32_16x16x32_bf16(ah, bl, acc_z, 0,0,0);
      acc_z = __builtin_amdgcn_mfma_f32_16x16x32_bf16(al, bh, acc_z, 0,0,0);
      bh = *(const bf16x8*)(wfr + (2*ks + 0) * 512);
      bl = *(const bf16x8*)(wfr + (2*ks + 1) * 512);
      acc_r = __builtin_amdgcn_mfma_f32_16x16x32_bf16(ah, bh, acc_r, 0,0,0);
      acc_r = __builtin_amdgcn_mfma_f32_16x16x32_bf16(ah, bl, acc_r, 0,0,0);
      acc_r = __builtin_amdgcn_mfma_f32_16x16x32_bf16(al, bh, acc_r, 0,0,0);
      bh = *(const bf16x8*)(wfh + (2*ks + 0) * 512);
      bl = *(const bf16x8*)(wfh + (2*ks + 1) * 512);
      acc_rh = __builtin_amdgcn_mfma_f32_16x16x32_bf16(ah, bh, acc_rh, 0,0,0);
      acc_rh = __builtin_amdgcn_mfma_f32_16x16x32_bf16(ah, bl, acc_rh, 0,0,0);
      acc_rh = __builtin_amdgcn_mfma_f32_16x16x32_bf16(al, bh, acc_rh, 0,0,0);
    }
    // ks 4..5: A from s (input part)
    #pragma unroll 2
    for (int ks = 4; ks < 6; ++ks) {
      const int off = 32*(ks - 4) + 8*kg;
      bf16x8 ah = *(const bf16x8*)&s_hi[rbase + fr][off];
      bf16x8 al = *(const bf16x8*)&s_lo[rbase + fr][off];
      bf16x8 bh = *(const bf16x8*)(wfz + (2*ks + 0) * 512);
      bf16x8 bl = *(const bf16x8*)(wfz + (2*ks + 1) * 512);
      acc_z = __builtin_amdgcn_mfma_f32_16x16x32_bf16(ah, bh, acc_z, 0,0,0);
      acc_z = __builtin_amdgcn_mfma_f32_16x16x32_bf16(ah, bl, acc_z, 0,0,0);
      acc_z = __builtin_amdgcn_mfma_f32_16x16x32_bf16(al, bh, acc_z, 0,0,0);
      bh = *(const bf16x8*)(wfr + (2*ks + 0) * 512);
      bl = *(const bf16x8*)(wfr + (2*ks + 1) * 512);
      acc_r = __builtin_amdgcn_mfma_f32_16x16x32_bf16(ah, bh, acc_r, 0,0,0);
      acc_r = __builtin_amdgcn_mfma_f32_16x16x32_bf16(ah, bl, acc_r, 0,0,0);
      acc_r = __builtin_amdgcn_mfma_f32_16x16x32_bf16(al, bh, acc_r, 0,0,0);
      bh = *(const bf16x8*)(wfh + (2*ks + 0) * 512);
      bl = *(const bf16x8*)(wfh + (2*ks + 1) * 512);
      acc_xh = __builtin_amdgcn_mfma_f32_16x16x32_bf16(ah, bh, acc_xh, 0,0,0);
      acc_xh = __builtin_amdgcn_mfma_f32_16x16x32_bf16(ah, bl, acc_xh, 0,0,0);
      acc_xh = __builtin_amdgcn_mfma_f32_16x16x32_bf16(al, bh, acc_xh, 0,0,0);
    }
    // D layout: col = lane&15, row = 4*(lane>>4)+j  [verified m89/m91]
    const int orow = rbase + 4 * kg;
    const int c    = 16 * g3 + fr;
    #pragma unroll
    for (int j = 0; j < 4; ++j) {
      m_zr[orow + j][c]         = acc_z[j];
      m_zr[orow + j][UNITS + c] = acc_r[j];
      m_rh[orow + j][c]         = acc_rh[j];
      m_xh[orow + j][c]         = acc_xh[j];
    }
  };

  // ---- gate elementwise + h update + bf16 split ----
  auto combine = [&]() {
    #pragma unroll
    for (int j = 0; j < 4; ++j) {
      const int r = rb4 + j;
      float az = m_zr[r][cu]         + bz;
      float ar = m_zr[r][UNITS + cu] + brg;
      float rh = m_rh[r][cu]         + brh;
      float xh = m_xh[r][cu]         + bxh;
      float z  = sigmoid_f(az);
      float rr = sigmoid_f(ar);
      float hh = tanhf(fmaf(rr, rh, xh));
      float h  = z * hreg[j] + (1.0f - z) * hh;
      hreg[j]  = h;
      h_f32[r][cu] = h;
      ushort_t hi = f2bf(h);
      h_hi[r][cu] = hi;
      h_lo[r][cu] = f2bf(h - bf2f(hi));
    }
  };

  // ---- f32 head GEMM: t = h @ K_g + b_g ----
  const int tc  = tid & 127;
  const int trg = tid >> 7;
  auto tgemm = [&](int g) {
    if (tc < OUT_C) {
      const float* K = Wdec + (size_t)g * NW;
      float acc[4] = {};
      #pragma unroll 2
      for (int kk = 0; kk < UNITS; kk += 4) {
        float kw[4];
        #pragma unroll
        for (int q = 0; q < 4; ++q) kw[q] = K[(kk + q) * OUT_C + tc];
        #pragma unroll
        for (int r = 0; r < 4; ++r) {
          float4 h4 = *(const float4*)&h_f32[trg * 4 + r][kk];
          acc[r] = fmaf(h4.x, kw[0], acc[r]); acc[r] = fmaf(h4.y, kw[1], acc[r]);
          acc[r] = fmaf(h4.z, kw[2], acc[r]); acc[r] = fmaf(h4.w, kw[3], acc[r]);
        }
      }
      float kb = K[UNITS * OUT_C + tc];
      #pragma unroll
      for (int r = 0; r < 4; ++r) {
        float tv = acc[r] + kb;
        t_lds[trg * 4 + r][tc] = tv;
        float ov = (tc < NF) ? tv
                             : (1e-5f + 0.05f * softplus_f(CCONST + tv));
        out[(size_t)(b0 + trg * 4 + r) * (GAMMA * OUT_C) + g * OUT_C + tc] = ov;
      }
    }
  };

  // ---- decoder input: s = loc + scale * eps_s[j] (split to bf16 hi/lo) ----
  auto sphase = [&](int j) {
    for (int idx = tid; idx < BR * NF; idx += THREADS) {
      int r = idx / NF, f = idx - r * NF;
      float loc = t_lds[r][f];
      float sc = 1e-5f + 0.05f * softplus_f(CCONST + t_lds[r][NF + f]);
      uint32_t gi = (uint32_t)((j * BATCH + b0 + r) * NF + f);
      float es = jax_normal(ks0, ks1, gi);
      float s = fmaf(sc, es, loc);
      ushort_t hi = f2bf(s);
      s_hi[r][f] = hi;
      s_lo[r][f] = f2bf(s - bf2f(hi));
    }
  };

  // ---- encoder: 50 steps ----
  for (int t = 0; t < TSTEPS; ++t) {
    for (int idx = tid; idx < BR * NF; idx += THREADS) {
      int r = idx / NF, f = idx - r * NF;
      float v = x[(size_t)(b0 + r) * (SEQ_T * NF) + t * NF + f];
      ushort_t hi = f2bf(v);
      s_hi[r][f] = hi;
      s_lo[r][f] = f2bf(v - bf2f(hi));
    }
    __syncthreads();
    gemm_phase();
    __syncthreads();
    combine();
    __syncthreads();
  }
  tgemm(0);
  __syncthreads();

  // ---- decoder: 27 steps ----
  for (int j = 0; j < NDEC; ++j) {
    sphase(j);
    __syncthreads();
    gemm_phase();
    __syncthreads();
    combine();
    __syncthreads();
    tgemm(j + 1);
    __syncthreads();
  }
}

extern "C" void kernel_launch(void* const* d_in, const int* in_sizes, int n_in,
                              void* d_out, int out_size, void* d_ws, size_t ws_size,
                              hipStream_t stream)
{
  const float* x    = (const float*)d_in[0];
  const float* gk   = (const float*)d_in[1];   // (51, 384)
  const float* grk  = (const float*)d_in[2];   // (128, 384)
  const float* gb   = (const float*)d_in[3];
  const float* ploc = (const float*)d_in[4];
  const float* prho = (const float*)d_in[5];

  float* wdec = (float*)d_ws;                          // 368424 floats (1.47 MB)
  ushort_t* wf = (ushort_t*)(wdec + KW_ELEMS);         // 147456 ushorts (288 KB)

  uint32_t kw0, kw1, ksd0, ksd1;
  tf2x32(0u, 42u, 0u, 0u, kw0, kw1);
  tf2x32(0u, 42u, 0u, 1u, ksd0, ksd1);

  sample_w_kernel<<<(KW_ELEMS + 255) / 256, 256, 0, stream>>>(ploc, prho, wdec, kw0, kw1);
  build_wf_kernel<<<(WF_USHORTS + 255) / 256, 256, 0, stream>>>(grk, gk, wf);
  irnn_main<<<BATCH / BR, THREADS, 0, stream>>>(x, gb, wdec, wf,
                                                (float*)d_out, ksd0, ksd1);
}

// Round 3
// 704.183 us; speedup vs baseline: 3.3191x; 1.6306x over previous
//
#include <hip/hip_runtime.h>
#include <stdint.h>

#define NF 51
#define UNITS 128
#define G3 384
#define OUT_C 102
#define NW 13158            // UNITS*OUT_C + OUT_C
#define GAMMA 28
#define BATCH 8192
#define SEQ_T 64
#define TSTEPS 50           // 64 - LAG(14)
#define NDEC 27
#define BR 32               // batch rows per block
#define THREADS 1024        // 16 waves
#define CCONST 0.5413248546129181f
#define WF_USHORTS 147456   // 24 nb * 6 ks * 2 split * 512
#define WDF_USHORTS 802816  // 28 g * 7 nt * 4 ks * 2 split * 512
#define WDF_FRAG_THREADS 401408  // 28*7*4*64*8
#define HB_ELEMS 2856       // 28 * 102

typedef __attribute__((ext_vector_type(8))) short bf16x8;
typedef __attribute__((ext_vector_type(4))) float f32x4;
typedef unsigned short ushort_t;

// ---------- JAX threefry2x32 (20 rounds), host+device ----------
__host__ __device__ __forceinline__ void tf2x32(uint32_t k0, uint32_t k1,
    uint32_t x0, uint32_t x1, uint32_t& o0, uint32_t& o1)
{
  uint32_t ks2 = k0 ^ k1 ^ 0x1BD11BDAu;
  x0 += k0; x1 += k1;
#define TF_R(r) { x0 += x1; x1 = (x1 << (r)) | (x1 >> (32 - (r))); x1 ^= x0; }
  TF_R(13) TF_R(15) TF_R(26) TF_R(6)  x0 += k1;  x1 += ks2 + 1u;
  TF_R(17) TF_R(29) TF_R(16) TF_R(24) x0 += ks2; x1 += k0 + 2u;
  TF_R(13) TF_R(15) TF_R(26) TF_R(6)  x0 += k0;  x1 += k1 + 3u;
  TF_R(17) TF_R(29) TF_R(16) TF_R(24) x0 += k1;  x1 += ks2 + 4u;
  TF_R(13) TF_R(15) TF_R(26) TF_R(6)  x0 += ks2; x1 += k0 + 5u;
#undef TF_R
  o0 = x0; o1 = x1;
}

// XLA ErfInv32 (Giles)
__device__ __forceinline__ float erfinv_f(float x) {
  float w = -log1pf(-x * x);
  float p;
  if (w < 5.0f) {
    w -= 2.5f;
    p = 2.81022636e-08f;
    p = fmaf(p, w, 3.43273939e-07f);
    p = fmaf(p, w, -3.5233877e-06f);
    p = fmaf(p, w, -4.39150654e-06f);
    p = fmaf(p, w, 0.00021858087f);
    p = fmaf(p, w, -0.00125372503f);
    p = fmaf(p, w, -0.00417768164f);
    p = fmaf(p, w, 0.246640727f);
    p = fmaf(p, w, 1.50140941f);
  } else {
    w = sqrtf(w) - 3.0f;
    p = -0.000200214257f;
    p = fmaf(p, w, 0.000100950558f);
    p = fmaf(p, w, 0.00134934322f);
    p = fmaf(p, w, -0.00367342844f);
    p = fmaf(p, w, 0.00573950773f);
    p = fmaf(p, w, -0.0076224613f);
    p = fmaf(p, w, 0.00943887047f);
    p = fmaf(p, w, 1.00167406f);
    p = fmaf(p, w, 2.83297682f);
  }
  return p * x;
}

__device__ __forceinline__ float jax_normal(uint32_t k0, uint32_t k1, uint32_t i)
{
  uint32_t y0, y1;
  tf2x32(k0, k1, 0u, i, y0, y1);
  uint32_t bits = y0 ^ y1;
  uint32_t fb = (bits >> 9) | 0x3f800000u;
  float f = __uint_as_float(fb) - 1.0f;       // [0,1)
  const float lo = -0.99999994f;
  const float d  = 1.99999994f;
  float u = __fadd_rn(__fmul_rn(f, d), lo);   // XLA uses mul+add (no fma)
  u = fmaxf(lo, u);
  return 1.41421354f * erfinv_f(u);
}

__device__ __forceinline__ float softplus_f(float x) {
  return fmaxf(x, 0.0f) + log1pf(expf(-fabsf(x)));
}
// fast gate nonlinearities: v_exp + v_rcp, ~1e-6 abs error (gates only)
__device__ __forceinline__ float rcp_f(float x) { return __builtin_amdgcn_rcpf(x); }
__device__ __forceinline__ float sigmoid_fast(float x) {
  return rcp_f(1.0f + __expf(-x));
}
__device__ __forceinline__ float tanh_fast(float x) {
  return 1.0f - 2.0f * rcp_f(1.0f + __expf(2.0f * x));  // saturates correctly
}

// f32 <-> bf16 bits (RNE)
__device__ __forceinline__ ushort_t f2bf(float f) {
  uint32_t u = __float_as_uint(f);
  uint32_t r = (u + 0x7fffu + ((u >> 16) & 1u)) >> 16;
  return (ushort_t)r;
}
__device__ __forceinline__ float bf2f(ushort_t h) {
  return __uint_as_float(((uint32_t)h) << 16);
}

// ---------- prep kernel 1: GRU weights -> MFMA B-fragments (split-bf16) ----
// Layout: WF[nb(24)][ks(6)][split(2)][lane(64)][elem(8)] ushorts.
// nb = 16-col tile of 384 gate cols. ks 0..3 = Wh rows, ks 4..5 = Wx (padded).
__global__ void build_wf_kernel(const float* __restrict__ Wh,   // (128,384)
                                const float* __restrict__ Wx,   // (51,384)
                                ushort_t* __restrict__ wf)
{
  int t = blockIdx.x * 256 + threadIdx.x;
  if (t >= WF_USHORTS) return;
  int e    = t & 7;
  int lane = (t >> 3) & 63;
  int sp   = (t >> 9) & 1;
  int q    = t >> 10;          // nb*6 + ks
  int ks   = q % 6;
  int nb   = q / 6;
  int kl   = 8 * (lane >> 4) + e;
  int col  = 16 * nb + (lane & 15);
  float w;
  if (ks < 4) {
    w = Wh[(32 * ks + kl) * G3 + col];
  } else {
    int row = 32 * (ks - 4) + kl;
    w = (row < NF) ? Wx[row * G3 + col] : 0.0f;
  }
  ushort_t hi = f2bf(w);
  wf[t] = (sp == 0) ? hi : f2bf(w - bf2f(hi));
}

// ---------- prep kernel 2: sample decoder weights DIRECTLY into fragments ----
// WDF[g(28)*7+nt][ks(4)][split(2)][lane(64)][elem(8)]; cols>=102 zero-padded.
// Plus hbias[g][col] f32.
__global__ void build_wdf_kernel(const float* __restrict__ post_loc,
                                 const float* __restrict__ post_rho,
                                 ushort_t* __restrict__ wdf,
                                 float* __restrict__ hbias,
                                 uint32_t kw0, uint32_t kw1)
{
  int t = blockIdx.x * 256 + threadIdx.x;
  if (t < WDF_FRAG_THREADS) {
    int e    = t & 7;
    int lane = (t >> 3) & 63;
    int ks   = (t >> 9) & 3;
    int q    = t >> 11;          // g*7 + nt
    int nt   = q % 7;
    int g    = q / 7;
    int k    = 32 * ks + 8 * (lane >> 4) + e;
    int col  = 16 * nt + (lane & 15);
    float w = 0.0f;
    if (col < OUT_C) {
      int widx = k * OUT_C + col;
      float eps = jax_normal(kw0, kw1, (uint32_t)(g * NW + widx));
      float sc = 1e-5f + 0.02f * softplus_f(CCONST + post_rho[widx]);
      w = fmaf(sc, eps, post_loc[widx]);
    }
    ushort_t hi = f2bf(w);
    size_t base = (size_t)(q * 4 + ks) * 1024 + lane * 8 + e;
    wdf[base]       = hi;
    wdf[base + 512] = f2bf(w - bf2f(hi));
  } else if (t < WDF_FRAG_THREADS + HB_ELEMS) {
    int u = t - WDF_FRAG_THREADS;
    int col = u % OUT_C, g = u / OUT_C;
    int widx = UNITS * OUT_C + col;
    float eps = jax_normal(kw0, kw1, (uint32_t)(g * NW + widx));
    float sc = 1e-5f + 0.02f * softplus_f(CCONST + post_rho[widx]);
    hbias[u] = fmaf(sc, eps, post_loc[widx]);
  }
}

// ---------- main kernel ----------
// GRU: 48 tiles (2m x 24n) over 16 waves = 3 tiles/wave sharing one m-row.
// Gates computed IN-REGISTER in the MFMA wave: D-frag (row=rbase+4kg+j,
// unit c=16g3+fr) holds z,r,rh,xh for the same (row,unit) in one thread ->
// no m_* LDS round-trip, no combine phase. hreg[j] carries h across steps.
// Head GEMM also on MFMA (waves 0..13, 14 tiles of 2m x 7n).
__global__ __launch_bounds__(THREADS, 4)
__attribute__((amdgpu_waves_per_eu(4, 4)))
void irnn_main(
    const float* __restrict__ x,      // (8192, 64, 51)
    const float* __restrict__ gbias,  // (2, 384)
    const ushort_t* __restrict__ WF,  // GRU fragment weights
    const ushort_t* __restrict__ WDF, // head fragment weights
    const float* __restrict__ HB,     // head bias (28,102)
    float* __restrict__ out,          // (8192, 28, 102)
    uint32_t ks0, uint32_t ks1)
{
  __shared__ __align__(16) ushort_t h_hi[BR][136];   // bf16 hi, pad 128->136
  __shared__ __align__(16) ushort_t h_lo[BR][136];
  __shared__ __align__(16) ushort_t s_hi[BR][72];    // K-pad 52..63 zero
  __shared__ __align__(16) ushort_t s_lo[BR][72];
  __shared__ float t_lds[BR][OUT_C];

  const int tid  = threadIdx.x;
  const int b0   = blockIdx.x * BR;
  const int lane = tid & 63;
  const int wv   = tid >> 6;          // 0..15
  const int kg   = lane >> 4;         // k-group 0..3
  const int fr   = lane & 15;         // frag row (A) / col (B,D)
  const int g3   = wv >> 1;           // 0..7 -> n-tile group
  const int rbase = 16 * (wv & 1);    // m-tile base row
  const int c    = 16 * g3 + fr;      // unit column owned by this thread

  // gate biases for unit c
  const float bz  = gbias[c]           + gbias[G3 + c];
  const float brg = gbias[UNITS + c]   + gbias[G3 + UNITS + c];
  const float bxh = gbias[2*UNITS + c];
  const float brh = gbias[G3 + 2*UNITS + c];

  float hreg[4] = {0.f, 0.f, 0.f, 0.f};   // h at (rbase+4kg+j, c)

  for (int i = tid; i < BR * 136; i += THREADS) { (&h_hi[0][0])[i] = 0; (&h_lo[0][0])[i] = 0; }
  for (int i = tid; i < BR * 72;  i += THREADS) { (&s_hi[0][0])[i] = 0; (&s_lo[0][0])[i] = 0; }
  __syncthreads();

  const ushort_t* wfz = WF + (size_t)g3        * 6144 + (size_t)lane * 8;
  const ushort_t* wfr = WF + (size_t)(8 + g3)  * 6144 + (size_t)lane * 8;
  const ushort_t* wfh = WF + (size_t)(16 + g3) * 6144 + (size_t)lane * 8;

  // ---- GRU step: MFMA + in-register gates; internal barrier guards h RAW ----
  auto gru_phase = [&]() {
    f32x4 acc_z  = {0.f,0.f,0.f,0.f};
    f32x4 acc_r  = {0.f,0.f,0.f,0.f};
    f32x4 acc_rh = {0.f,0.f,0.f,0.f};
    f32x4 acc_xh = {0.f,0.f,0.f,0.f};
    // ks 0..3: A from h (recurrent part)
    #pragma unroll 2
    for (int ks = 0; ks < 4; ++ks) {
      const int off = 32*ks + 8*kg;
      bf16x8 ah = *(const bf16x8*)&h_hi[rbase + fr][off];
      bf16x8 al = *(const bf16x8*)&h_lo[rbase + fr][off];
      bf16x8 bh = *(const bf16x8*)(wfz + (2*ks + 0) * 512);
      bf16x8 bl = *(const bf16x8*)(wfz + (2*ks + 1) * 512);
      acc_z = __builtin_amdgcn_mfma_f32_16x16x32_bf16(ah, bh, acc_z, 0,0,0);
      acc_z = __builtin_amdgcn_mfma_f32_16x16x32_bf16(ah, bl, acc_z, 0,0,0);
      acc_z = __builtin_amdgcn_mfma_f32_16x16x32_bf16(al, bh, acc_z, 0,0,0);
      bh = *(const bf16x8*)(wfr + (2*ks + 0) * 512);
      bl = *(const bf16x8*)(wfr + (2*ks + 1) * 512);
      acc_r = __builtin_amdgcn_mfma_f32_16x16x32_bf16(ah, bh, acc_r, 0,0,0);
      acc_r = __builtin_amdgcn_mfma_f32_16x16x32_bf16(ah, bl, acc_r, 0,0,0);
      acc_r = __builtin_amdgcn_mfma_f32_16x16x32_bf16(al, bh, acc_r, 0,0,0);
      bh = *(const bf16x8*)(wfh + (2*ks + 0) * 512);
      bl = *(const bf16x8*)(wfh + (2*ks + 1) * 512);
      acc_rh = __builtin_amdgcn_mfma_f32_16x16x32_bf16(ah, bh, acc_rh, 0,0,0);
      acc_rh = __builtin_amdgcn_mfma_f32_16x16x32_bf16(ah, bl, acc_rh, 0,0,0);
      acc_rh = __builtin_amdgcn_mfma_f32_16x16x32_bf16(al, bh, acc_rh, 0,0,0);
    }
    // ks 4..5: A from s (input part)
    #pragma unroll 2
    for (int ks = 4; ks < 6; ++ks) {
      const int off = 32*(ks - 4) + 8*kg;
      bf16x8 ah = *(const bf16x8*)&s_hi[rbase + fr][off];
      bf16x8 al = *(const bf16x8*)&s_lo[rbase + fr][off];
      bf16x8 bh = *(const bf16x8*)(wfz + (2*ks + 0) * 512);
      bf16x8 bl = *(const bf16x8*)(wfz + (2*ks + 1) * 512);
      acc_z = __builtin_amdgcn_mfma_f32_16x16x32_bf16(ah, bh, acc_z, 0,0,0);
      acc_z = __builtin_amdgcn_mfma_f32_16x16x32_bf16(ah, bl, acc_z, 0,0,0);
      acc_z = __builtin_amdgcn_mfma_f32_16x16x32_bf16(al, bh, acc_z, 0,0,0);
      bh = *(const bf16x8*)(wfr + (2*ks + 0) * 512);
      bl = *(const bf16x8*)(wfr + (2*ks + 1) * 512);
      acc_r = __builtin_amdgcn_mfma_f32_16x16x32_bf16(ah, bh, acc_r, 0,0,0);
      acc_r = __builtin_amdgcn_mfma_f32_16x16x32_bf16(ah, bl, acc_r, 0,0,0);
      acc_r = __builtin_amdgcn_mfma_f32_16x16x32_bf16(al, bh, acc_r, 0,0,0);
      bh = *(const bf16x8*)(wfh + (2*ks + 0) * 512);
      bl = *(const bf16x8*)(wfh + (2*ks + 1) * 512);
      acc_xh = __builtin_amdgcn_mfma_f32_16x16x32_bf16(ah, bh, acc_xh, 0,0,0);
      acc_xh = __builtin_amdgcn_mfma_f32_16x16x32_bf16(ah, bl, acc_xh, 0,0,0);
      acc_xh = __builtin_amdgcn_mfma_f32_16x16x32_bf16(al, bh, acc_xh, 0,0,0);
    }
    // all reads of h_hi/h_lo complete before anyone overwrites them
    __syncthreads();
    const int orow = rbase + 4 * kg;
    #pragma unroll
    for (int j = 0; j < 4; ++j) {
      float az = acc_z[j]  + bz;
      float ar = acc_r[j]  + brg;
      float rh = acc_rh[j] + brh;
      float xh = acc_xh[j] + bxh;
      float z  = sigmoid_fast(az);
      float rr = sigmoid_fast(ar);
      float hh = tanh_fast(fmaf(rr, rh, xh));
      float h  = z * hreg[j] + (1.0f - z) * hh;
      hreg[j]  = h;
      ushort_t hi = f2bf(h);
      h_hi[orow + j][c] = hi;
      h_lo[orow + j][c] = f2bf(h - bf2f(hi));
    }
  };

  // ---- head: t = h @ K_g + b_g on MFMA (waves 0..13: 2m x 7n tiles) ----
  auto head = [&](int g) {
    if (wv < 14) {
      const int nt = wv % 7, mt = wv / 7;
      const ushort_t* WB = WDF + (size_t)(g * 7 + nt) * 4096 + (size_t)lane * 8;
      f32x4 acc = {0.f,0.f,0.f,0.f};
      #pragma unroll 2
      for (int ks = 0; ks < 4; ++ks) {
        const int off = 32*ks + 8*kg;
        bf16x8 ah = *(const bf16x8*)&h_hi[16*mt + fr][off];
        bf16x8 al = *(const bf16x8*)&h_lo[16*mt + fr][off];
        bf16x8 bh = *(const bf16x8*)(WB + (2*ks + 0) * 512);
        bf16x8 bl = *(const bf16x8*)(WB + (2*ks + 1) * 512);
        acc = __builtin_amdgcn_mfma_f32_16x16x32_bf16(ah, bh, acc, 0,0,0);
        acc = __builtin_amdgcn_mfma_f32_16x16x32_bf16(ah, bl, acc, 0,0,0);
        acc = __builtin_amdgcn_mfma_f32_16x16x32_bf16(al, bh, acc, 0,0,0);
      }
      const int col = 16*nt + fr;
      if (col < OUT_C) {
        float kb = HB[g * OUT_C + col];
        const int r0 = 16*mt + 4*kg;
        #pragma unroll
        for (int j = 0; j < 4; ++j) {
          float tv = acc[j] + kb;
          t_lds[r0 + j][col] = tv;
          float ov = (col < NF) ? tv
                               : (1e-5f + 0.05f * softplus_f(CCONST + tv));
          out[(size_t)(b0 + r0 + j) * (GAMMA * OUT_C) + g * OUT_C + col] = ov;
        }
      }
    }
  };

  // ---- decoder input: s = loc + scale * eps_s[j] (split to bf16 hi/lo) ----
  auto sphase = [&](int j) {
    for (int idx = tid; idx < BR * NF; idx += THREADS) {
      int r = idx / NF, f = idx - r * NF;
      float loc = t_lds[r][f];
      float sc = 1e-5f + 0.05f * softplus_f(CCONST + t_lds[r][NF + f]);
      uint32_t gi = (uint32_t)((j * BATCH + b0 + r) * NF + f);
      float es = jax_normal(ks0, ks1, gi);
      float s = fmaf(sc, es, loc);
      ushort_t hi = f2bf(s);
      s_hi[r][f] = hi;
      s_lo[r][f] = f2bf(s - bf2f(hi));
    }
  };

  // ---- encoder: 50 steps, 2 barriers/step ----
  for (int t = 0; t < TSTEPS; ++t) {
    for (int idx = tid; idx < BR * NF; idx += THREADS) {
      int r = idx / NF, f = idx - r * NF;
      float v = x[(size_t)(b0 + r) * (SEQ_T * NF) + t * NF + f];
      ushort_t hi = f2bf(v);
      s_hi[r][f] = hi;
      s_lo[r][f] = f2bf(v - bf2f(hi));
    }
    __syncthreads();
    gru_phase();        // internal barrier before h-write
  }
  __syncthreads();      // h visible
  head(0);
  __syncthreads();      // t_lds visible

  // ---- decoder: 27 steps, 4 barriers/step ----
  for (int j = 0; j < NDEC; ++j) {
    sphase(j);
    __syncthreads();
    gru_phase();
    __syncthreads();    // h-writes visible to head
    head(j + 1);
    __syncthreads();    // t_lds visible to next sphase
  }
}

extern "C" void kernel_launch(void* const* d_in, const int* in_sizes, int n_in,
                              void* d_out, int out_size, void* d_ws, size_t ws_size,
                              hipStream_t stream)
{
  const float* x    = (const float*)d_in[0];
  const float* gk   = (const float*)d_in[1];   // (51, 384)
  const float* grk  = (const float*)d_in[2];   // (128, 384)
  const float* gb   = (const float*)d_in[3];
  const float* ploc = (const float*)d_in[4];
  const float* prho = (const float*)d_in[5];

  ushort_t* wf  = (ushort_t*)d_ws;                 // 294912 B
  ushort_t* wdf = wf + WF_USHORTS;                 // 1605632 B
  float*    hb  = (float*)(wdf + WDF_USHORTS);     // 11424 B

  uint32_t kw0, kw1, ksd0, ksd1;
  tf2x32(0u, 42u, 0u, 0u, kw0, kw1);
  tf2x32(0u, 42u, 0u, 1u, ksd0, ksd1);

  build_wf_kernel<<<(WF_USHORTS + 255) / 256, 256, 0, stream>>>(grk, gk, wf);
  build_wdf_kernel<<<(WDF_FRAG_THREADS + HB_ELEMS + 255) / 256, 256, 0, stream>>>(
      ploc, prho, wdf, hb, kw0, kw1);
  irnn_main<<<BATCH / BR, THREADS, 0, stream>>>(x, gb, wf, wdf, hb,
                                                (float*)d_out, ksd0, ksd1);
}

// Round 4
// 666.451 us; speedup vs baseline: 3.5070x; 1.0566x over previous
//
#include <hip/hip_runtime.h>
#include <stdint.h>

#define NF 51
#define UNITS 128
#define G3 384
#define OUT_C 102
#define NW 13158            // UNITS*OUT_C + OUT_C
#define GAMMA 28
#define BATCH 8192
#define SEQ_T 64
#define TSTEPS 50           // 64 - LAG(14)
#define NDEC 27
#define BR 32               // batch rows per block
#define THREADS 1024        // 16 waves
#define CCONST 0.5413248546129181f
#define WF_USHORTS 147456   // 24 nb * 6 ks * 2 split * 512
#define WDF_USHORTS 802816  // 28 g * 7 nt * 4 ks * 2 split * 512
#define WDF_FRAG_THREADS 401408  // 28*7*4*64*8
#define HB_ELEMS 2856       // 28 * 102

typedef __attribute__((ext_vector_type(8))) short bf16x8;
typedef __attribute__((ext_vector_type(4))) float f32x4;
typedef unsigned short ushort_t;

// ---------- JAX threefry2x32 (20 rounds), host+device ----------
__host__ __device__ __forceinline__ void tf2x32(uint32_t k0, uint32_t k1,
    uint32_t x0, uint32_t x1, uint32_t& o0, uint32_t& o1)
{
  uint32_t ks2 = k0 ^ k1 ^ 0x1BD11BDAu;
  x0 += k0; x1 += k1;
#define TF_R(r) { x0 += x1; x1 = (x1 << (r)) | (x1 >> (32 - (r))); x1 ^= x0; }
  TF_R(13) TF_R(15) TF_R(26) TF_R(6)  x0 += k1;  x1 += ks2 + 1u;
  TF_R(17) TF_R(29) TF_R(16) TF_R(24) x0 += ks2; x1 += k0 + 2u;
  TF_R(13) TF_R(15) TF_R(26) TF_R(6)  x0 += k0;  x1 += k1 + 3u;
  TF_R(17) TF_R(29) TF_R(16) TF_R(24) x0 += k1;  x1 += ks2 + 4u;
  TF_R(13) TF_R(15) TF_R(26) TF_R(6)  x0 += ks2; x1 += k0 + 5u;
#undef TF_R
  o0 = x0; o1 = x1;
}

// XLA ErfInv32 (Giles)
__device__ __forceinline__ float erfinv_f(float x) {
  float w = -log1pf(-x * x);
  float p;
  if (w < 5.0f) {
    w -= 2.5f;
    p = 2.81022636e-08f;
    p = fmaf(p, w, 3.43273939e-07f);
    p = fmaf(p, w, -3.5233877e-06f);
    p = fmaf(p, w, -4.39150654e-06f);
    p = fmaf(p, w, 0.00021858087f);
    p = fmaf(p, w, -0.00125372503f);
    p = fmaf(p, w, -0.00417768164f);
    p = fmaf(p, w, 0.246640727f);
    p = fmaf(p, w, 1.50140941f);
  } else {
    w = sqrtf(w) - 3.0f;
    p = -0.000200214257f;
    p = fmaf(p, w, 0.000100950558f);
    p = fmaf(p, w, 0.00134934322f);
    p = fmaf(p, w, -0.00367342844f);
    p = fmaf(p, w, 0.00573950773f);
    p = fmaf(p, w, -0.0076224613f);
    p = fmaf(p, w, 0.00943887047f);
    p = fmaf(p, w, 1.00167406f);
    p = fmaf(p, w, 2.83297682f);
  }
  return p * x;
}

__device__ __forceinline__ float jax_normal(uint32_t k0, uint32_t k1, uint32_t i)
{
  uint32_t y0, y1;
  tf2x32(k0, k1, 0u, i, y0, y1);
  uint32_t bits = y0 ^ y1;
  uint32_t fb = (bits >> 9) | 0x3f800000u;
  float f = __uint_as_float(fb) - 1.0f;       // [0,1)
  const float lo = -0.99999994f;
  const float d  = 1.99999994f;
  float u = __fadd_rn(__fmul_rn(f, d), lo);   // XLA uses mul+add (no fma)
  u = fmaxf(lo, u);
  return 1.41421354f * erfinv_f(u);
}

__device__ __forceinline__ float softplus_f(float x) {
  return fmaxf(x, 0.0f) + log1pf(expf(-fabsf(x)));
}
// fast gate nonlinearities: v_exp + v_rcp, ~1e-6 abs error (gates only)
__device__ __forceinline__ float rcp_f(float x) { return __builtin_amdgcn_rcpf(x); }
__device__ __forceinline__ float sigmoid_fast(float x) {
  return rcp_f(1.0f + __expf(-x));
}
__device__ __forceinline__ float tanh_fast(float x) {
  return 1.0f - 2.0f * rcp_f(1.0f + __expf(2.0f * x));  // saturates correctly
}

// f32 <-> bf16 bits (RNE)
__device__ __forceinline__ ushort_t f2bf(float f) {
  uint32_t u = __float_as_uint(f);
  uint32_t r = (u + 0x7fffu + ((u >> 16) & 1u)) >> 16;
  return (ushort_t)r;
}
__device__ __forceinline__ float bf2f(ushort_t h) {
  return __uint_as_float(((uint32_t)h) << 16);
}

// ---------- prep kernel 1: GRU weights -> MFMA B-fragments (split-bf16) ----
// Layout: WF[nb(24)][ks(6)][split(2)][lane(64)][elem(8)] ushorts.
// nb = 16-col tile of 384 gate cols. ks 0..3 = Wh rows, ks 4..5 = Wx (padded).
__global__ void build_wf_kernel(const float* __restrict__ Wh,   // (128,384)
                                const float* __restrict__ Wx,   // (51,384)
                                ushort_t* __restrict__ wf)
{
  int t = blockIdx.x * 256 + threadIdx.x;
  if (t >= WF_USHORTS) return;
  int e    = t & 7;
  int lane = (t >> 3) & 63;
  int sp   = (t >> 9) & 1;
  int q    = t >> 10;          // nb*6 + ks
  int ks   = q % 6;
  int nb   = q / 6;
  int kl   = 8 * (lane >> 4) + e;
  int col  = 16 * nb + (lane & 15);
  float w;
  if (ks < 4) {
    w = Wh[(32 * ks + kl) * G3 + col];
  } else {
    int row = 32 * (ks - 4) + kl;
    w = (row < NF) ? Wx[row * G3 + col] : 0.0f;
  }
  ushort_t hi = f2bf(w);
  wf[t] = (sp == 0) ? hi : f2bf(w - bf2f(hi));
}

// ---------- prep kernel 2: sample decoder weights DIRECTLY into fragments ----
// WDF[g(28)*7+nt][ks(4)][split(2)][lane(64)][elem(8)]; cols>=102 zero-padded.
// Plus hbias[g][col] f32.
__global__ void build_wdf_kernel(const float* __restrict__ post_loc,
                                 const float* __restrict__ post_rho,
                                 ushort_t* __restrict__ wdf,
                                 float* __restrict__ hbias,
                                 uint32_t kw0, uint32_t kw1)
{
  int t = blockIdx.x * 256 + threadIdx.x;
  if (t < WDF_FRAG_THREADS) {
    int e    = t & 7;
    int lane = (t >> 3) & 63;
    int ks   = (t >> 9) & 3;
    int q    = t >> 11;          // g*7 + nt
    int nt   = q % 7;
    int g    = q / 7;
    int k    = 32 * ks + 8 * (lane >> 4) + e;
    int col  = 16 * nt + (lane & 15);
    float w = 0.0f;
    if (col < OUT_C) {
      int widx = k * OUT_C + col;
      float eps = jax_normal(kw0, kw1, (uint32_t)(g * NW + widx));
      float sc = 1e-5f + 0.02f * softplus_f(CCONST + post_rho[widx]);
      w = fmaf(sc, eps, post_loc[widx]);
    }
    ushort_t hi = f2bf(w);
    size_t base = (size_t)(q * 4 + ks) * 1024 + lane * 8 + e;
    wdf[base]       = hi;
    wdf[base + 512] = f2bf(w - bf2f(hi));
  } else if (t < WDF_FRAG_THREADS + HB_ELEMS) {
    int u = t - WDF_FRAG_THREADS;
    int col = u % OUT_C, g = u / OUT_C;
    int widx = UNITS * OUT_C + col;
    float eps = jax_normal(kw0, kw1, (uint32_t)(g * NW + widx));
    float sc = 1e-5f + 0.02f * softplus_f(CCONST + post_rho[widx]);
    hbias[u] = fmaf(sc, eps, post_loc[widx]);
  }
}

// ---------- main kernel ----------
// m-merged GRU: waves 0..7 each own the z/r/h tile triple for n-group g3=wv
// and BOTH 16-row m-tiles -> every B-fragment is loaded ONCE per block per
// step (288 KB/step vs 576 before; L2 stream was the bottleneck). 8 acc
// chains interleaved so dependent mfmas are ~29cy apart. Waves 8..15 are
// loader waves: encoder x(t+1) prefetch into double-buffered s.
// Gates remain fully in-register (hreg[8]); head on MFMA (waves 0..13).
__global__ __launch_bounds__(THREADS, 4)
__attribute__((amdgpu_waves_per_eu(4, 4)))
void irnn_main(
    const float* __restrict__ x,      // (8192, 64, 51)
    const float* __restrict__ gbias,  // (2, 384)
    const ushort_t* __restrict__ WF,  // GRU fragment weights
    const ushort_t* __restrict__ WDF, // head fragment weights
    const float* __restrict__ HB,     // head bias (28,102)
    float* __restrict__ out,          // (8192, 28, 102)
    uint32_t ks0, uint32_t ks1)
{
  __shared__ __align__(16) ushort_t h_hi[BR][136];     // bf16 hi, pad 128->136
  __shared__ __align__(16) ushort_t h_lo[BR][136];
  __shared__ __align__(16) ushort_t s_hi[2][BR][72];   // double-buffered
  __shared__ __align__(16) ushort_t s_lo[2][BR][72];   // (K-pad 52..63 zero)
  __shared__ float t_lds[BR][OUT_C];

  const int tid  = threadIdx.x;
  const int b0   = blockIdx.x * BR;
  const int lane = tid & 63;
  const int wv   = tid >> 6;          // 0..15
  const int kg   = lane >> 4;         // k-group 0..3
  const int fr   = lane & 15;         // frag row (A) / col (B,D)
  const int g3   = wv & 7;            // n-tile group (GRU waves: wv<8)
  const int c    = 16 * g3 + fr;      // unit column owned by this thread

  // gate biases for unit c
  const float bz  = gbias[c]           + gbias[G3 + c];
  const float brg = gbias[UNITS + c]   + gbias[G3 + UNITS + c];
  const float bxh = gbias[2*UNITS + c];
  const float brh = gbias[G3 + 2*UNITS + c];

  float hreg[8] = {0.f,0.f,0.f,0.f,0.f,0.f,0.f,0.f}; // h at (16m+4kg+j, c)
  f32x4 cz[2], cr[2], crh[2], cxh[2];                // GRU acc chains

  for (int i = tid; i < BR * 136; i += THREADS) { (&h_hi[0][0])[i] = 0; (&h_lo[0][0])[i] = 0; }
  for (int i = tid; i < 2 * BR * 72; i += THREADS) { (&s_hi[0][0][0])[i] = 0; (&s_lo[0][0][0])[i] = 0; }
  __syncthreads();

  const ushort_t* wfz = WF + (size_t)g3        * 6144 + (size_t)lane * 8;
  const ushort_t* wfr = WF + (size_t)(8 + g3)  * 6144 + (size_t)lane * 8;
  const ushort_t* wfh = WF + (size_t)(16 + g3) * 6144 + (size_t)lane * 8;

  // ---- GRU mfma: both m-tiles per wave, interleaved chains ----
  auto gru_mfma = [&](int buf) {
    #pragma unroll
    for (int m = 0; m < 2; ++m) {
      cz[m]  = (f32x4){0.f,0.f,0.f,0.f};
      cr[m]  = (f32x4){0.f,0.f,0.f,0.f};
      crh[m] = (f32x4){0.f,0.f,0.f,0.f};
      cxh[m] = (f32x4){0.f,0.f,0.f,0.f};
    }
    // ks 0..3: A from h (recurrent part), h-gate -> crh
    #pragma unroll 1
    for (int ks = 0; ks < 4; ++ks) {
      const int off = 32*ks + 8*kg;
      bf16x8 ah[2], al[2];
      ah[0] = *(const bf16x8*)&h_hi[fr][off];
      al[0] = *(const bf16x8*)&h_lo[fr][off];
      ah[1] = *(const bf16x8*)&h_hi[16 + fr][off];
      al[1] = *(const bf16x8*)&h_lo[16 + fr][off];
      bf16x8 bzh = *(const bf16x8*)(wfz + (2*ks + 0) * 512);
      bf16x8 bzl = *(const bf16x8*)(wfz + (2*ks + 1) * 512);
      bf16x8 brh_ = *(const bf16x8*)(wfr + (2*ks + 0) * 512);
      bf16x8 brl_ = *(const bf16x8*)(wfr + (2*ks + 1) * 512);
      bf16x8 bhh = *(const bf16x8*)(wfh + (2*ks + 0) * 512);
      bf16x8 bhl = *(const bf16x8*)(wfh + (2*ks + 1) * 512);
      #pragma unroll
      for (int m = 0; m < 2; ++m) cz[m]  = __builtin_amdgcn_mfma_f32_16x16x32_bf16(ah[m], bzh, cz[m], 0,0,0);
      #pragma unroll
      for (int m = 0; m < 2; ++m) cr[m]  = __builtin_amdgcn_mfma_f32_16x16x32_bf16(ah[m], brh_, cr[m], 0,0,0);
      #pragma unroll
      for (int m = 0; m < 2; ++m) crh[m] = __builtin_amdgcn_mfma_f32_16x16x32_bf16(ah[m], bhh, crh[m], 0,0,0);
      #pragma unroll
      for (int m = 0; m < 2; ++m) cz[m]  = __builtin_amdgcn_mfma_f32_16x16x32_bf16(ah[m], bzl, cz[m], 0,0,0);
      #pragma unroll
      for (int m = 0; m < 2; ++m) cr[m]  = __builtin_amdgcn_mfma_f32_16x16x32_bf16(ah[m], brl_, cr[m], 0,0,0);
      #pragma unroll
      for (int m = 0; m < 2; ++m) crh[m] = __builtin_amdgcn_mfma_f32_16x16x32_bf16(ah[m], bhl, crh[m], 0,0,0);
      #pragma unroll
      for (int m = 0; m < 2; ++m) cz[m]  = __builtin_amdgcn_mfma_f32_16x16x32_bf16(al[m], bzh, cz[m], 0,0,0);
      #pragma unroll
      for (int m = 0; m < 2; ++m) cr[m]  = __builtin_amdgcn_mfma_f32_16x16x32_bf16(al[m], brh_, cr[m], 0,0,0);
      #pragma unroll
      for (int m = 0; m < 2; ++m) crh[m] = __builtin_amdgcn_mfma_f32_16x16x32_bf16(al[m], bhh, crh[m], 0,0,0);
    }
    // ks 4..5: A from s (input part), h-gate -> cxh
    #pragma unroll 1
    for (int ks = 4; ks < 6; ++ks) {
      const int off = 32*(ks - 4) + 8*kg;
      bf16x8 ah[2], al[2];
      ah[0] = *(const bf16x8*)&s_hi[buf][fr][off];
      al[0] = *(const bf16x8*)&s_lo[buf][fr][off];
      ah[1] = *(const bf16x8*)&s_hi[buf][16 + fr][off];
      al[1] = *(const bf16x8*)&s_lo[buf][16 + fr][off];
      bf16x8 bzh = *(const bf16x8*)(wfz + (2*ks + 0) * 512);
      bf16x8 bzl = *(const bf16x8*)(wfz + (2*ks + 1) * 512);
      bf16x8 brh_ = *(const bf16x8*)(wfr + (2*ks + 0) * 512);
      bf16x8 brl_ = *(const bf16x8*)(wfr + (2*ks + 1) * 512);
      bf16x8 bhh = *(const bf16x8*)(wfh + (2*ks + 0) * 512);
      bf16x8 bhl = *(const bf16x8*)(wfh + (2*ks + 1) * 512);
      #pragma unroll
      for (int m = 0; m < 2; ++m) cz[m]  = __builtin_amdgcn_mfma_f32_16x16x32_bf16(ah[m], bzh, cz[m], 0,0,0);
      #pragma unroll
      for (int m = 0; m < 2; ++m) cr[m]  = __builtin_amdgcn_mfma_f32_16x16x32_bf16(ah[m], brh_, cr[m], 0,0,0);
      #pragma unroll
      for (int m = 0; m < 2; ++m) cxh[m] = __builtin_amdgcn_mfma_f32_16x16x32_bf16(ah[m], bhh, cxh[m], 0,0,0);
      #pragma unroll
      for (int m = 0; m < 2; ++m) cz[m]  = __builtin_amdgcn_mfma_f32_16x16x32_bf16(ah[m], bzl, cz[m], 0,0,0);
      #pragma unroll
      for (int m = 0; m < 2; ++m) cr[m]  = __builtin_amdgcn_mfma_f32_16x16x32_bf16(ah[m], brl_, cr[m], 0,0,0);
      #pragma unroll
      for (int m = 0; m < 2; ++m) cxh[m] = __builtin_amdgcn_mfma_f32_16x16x32_bf16(ah[m], bhl, cxh[m], 0,0,0);
      #pragma unroll
      for (int m = 0; m < 2; ++m) cz[m]  = __builtin_amdgcn_mfma_f32_16x16x32_bf16(al[m], bzh, cz[m], 0,0,0);
      #pragma unroll
      for (int m = 0; m < 2; ++m) cr[m]  = __builtin_amdgcn_mfma_f32_16x16x32_bf16(al[m], brh_, cr[m], 0,0,0);
      #pragma unroll
      for (int m = 0; m < 2; ++m) cxh[m] = __builtin_amdgcn_mfma_f32_16x16x32_bf16(al[m], bhh, cxh[m], 0,0,0);
    }
  };

  // ---- gate elementwise + h update + bf16 split (in-register) ----
  auto combine = [&]() {
    #pragma unroll
    for (int m = 0; m < 2; ++m) {
      const int orow = 16*m + 4*kg;
      #pragma unroll
      for (int j = 0; j < 4; ++j) {
        float az = cz[m][j]  + bz;
        float ar = cr[m][j]  + brg;
        float rh = crh[m][j] + brh;
        float xh = cxh[m][j] + bxh;
        float z  = sigmoid_fast(az);
        float rr = sigmoid_fast(ar);
        float hh = tanh_fast(fmaf(rr, rh, xh));
        float h  = z * hreg[4*m + j] + (1.0f - z) * hh;
        hreg[4*m + j] = h;
        ushort_t hi = f2bf(h);
        h_hi[orow + j][c] = hi;
        h_lo[orow + j][c] = f2bf(h - bf2f(hi));
      }
    }
  };

  // ---- head: t = h @ K_g + b_g on MFMA (waves 0..13: 2m x 7n tiles) ----
  auto head = [&](int g) {
    if (wv < 14) {
      const int nt = wv % 7, mt = wv / 7;
      const ushort_t* WB = WDF + (size_t)(g * 7 + nt) * 4096 + (size_t)lane * 8;
      f32x4 acc = {0.f,0.f,0.f,0.f};
      #pragma unroll 2
      for (int ks = 0; ks < 4; ++ks) {
        const int off = 32*ks + 8*kg;
        bf16x8 ah = *(const bf16x8*)&h_hi[16*mt + fr][off];
        bf16x8 al = *(const bf16x8*)&h_lo[16*mt + fr][off];
        bf16x8 bh = *(const bf16x8*)(WB + (2*ks + 0) * 512);
        bf16x8 bl = *(const bf16x8*)(WB + (2*ks + 1) * 512);
        acc = __builtin_amdgcn_mfma_f32_16x16x32_bf16(ah, bh, acc, 0,0,0);
        acc = __builtin_amdgcn_mfma_f32_16x16x32_bf16(ah, bl, acc, 0,0,0);
        acc = __builtin_amdgcn_mfma_f32_16x16x32_bf16(al, bh, acc, 0,0,0);
      }
      const int col = 16*nt + fr;
      if (col < OUT_C) {
        float kb = HB[g * OUT_C + col];
        const int r0 = 16*mt + 4*kg;
        #pragma unroll
        for (int j = 0; j < 4; ++j) {
          float tv = acc[j] + kb;
          t_lds[r0 + j][col] = tv;
          float ov = (col < NF) ? tv
                               : (1e-5f + 0.05f * softplus_f(CCONST + tv));
          out[(size_t)(b0 + r0 + j) * (GAMMA * OUT_C) + g * OUT_C + col] = ov;
        }
      }
    }
  };

  // ---- decoder input: s = loc + scale * eps_s[j] -> s buffer 0 ----
  auto sphase = [&](int j) {
    for (int idx = tid; idx < BR * NF; idx += THREADS) {
      int r = idx / NF, f = idx - r * NF;
      float loc = t_lds[r][f];
      float sc = 1e-5f + 0.05f * softplus_f(CCONST + t_lds[r][NF + f]);
      uint32_t gi = (uint32_t)((j * BATCH + b0 + r) * NF + f);
      float es = jax_normal(ks0, ks1, gi);
      float s = fmaf(sc, es, loc);
      ushort_t hi = f2bf(s);
      s_hi[0][r][f] = hi;
      s_lo[0][r][f] = f2bf(s - bf2f(hi));
    }
  };

  // ---- encoder: 50 steps; GRU waves compute while loader waves prefetch ----
  for (int idx = tid; idx < BR * NF; idx += THREADS) {   // preload x(0) -> s[0]
    int r = idx / NF, f = idx - r * NF;
    float v = x[(size_t)(b0 + r) * (SEQ_T * NF) + f];
    ushort_t hi = f2bf(v);
    s_hi[0][r][f] = hi;
    s_lo[0][r][f] = f2bf(v - bf2f(hi));
  }
  __syncthreads();
  for (int t = 0; t < TSTEPS; ++t) {
    if (wv < 8) {
      gru_mfma(t & 1);
    } else if (t + 1 < TSTEPS) {
      const int nb = (t + 1) & 1;
      for (int idx = tid - 512; idx < BR * NF; idx += 512) {
        int r = idx / NF, f = idx - r * NF;
        float v = x[(size_t)(b0 + r) * (SEQ_T * NF) + (t + 1) * NF + f];
        ushort_t hi = f2bf(v);
        s_hi[nb][r][f] = hi;
        s_lo[nb][r][f] = f2bf(v - bf2f(hi));
      }
    }
    __syncthreads();          // mfma h/s reads done; next-s written
    if (wv < 8) combine();
    __syncthreads();          // h visible
  }
  head(0);
  __syncthreads();            // t_lds visible

  // ---- decoder: 27 steps ----
  for (int j = 0; j < NDEC; ++j) {
    sphase(j);                // writes s buffer 0
    __syncthreads();
    if (wv < 8) gru_mfma(0);
    __syncthreads();          // mfma reads done
    if (wv < 8) combine();
    __syncthreads();          // h visible
    head(j + 1);
    __syncthreads();          // t_lds visible
  }
}

extern "C" void kernel_launch(void* const* d_in, const int* in_sizes, int n_in,
                              void* d_out, int out_size, void* d_ws, size_t ws_size,
                              hipStream_t stream)
{
  const float* x    = (const float*)d_in[0];
  const float* gk   = (const float*)d_in[1];   // (51, 384)
  const float* grk  = (const float*)d_in[2];   // (128, 384)
  const float* gb   = (const float*)d_in[3];
  const float* ploc = (const float*)d_in[4];
  const float* prho = (const float*)d_in[5];

  ushort_t* wf  = (ushort_t*)d_ws;                 // 294912 B
  ushort_t* wdf = wf + WF_USHORTS;                 // 1605632 B
  float*    hb  = (float*)(wdf + WDF_USHORTS);     // 11424 B

  uint32_t kw0, kw1, ksd0, ksd1;
  tf2x32(0u, 42u, 0u, 0u, kw0, kw1);
  tf2x32(0u, 42u, 0u, 1u, ksd0, ksd1);

  build_wf_kernel<<<(WF_USHORTS + 255) / 256, 256, 0, stream>>>(grk, gk, wf);
  build_wdf_kernel<<<(WDF_FRAG_THREADS + HB_ELEMS + 255) / 256, 256, 0, stream>>>(
      ploc, prho, wdf, hb, kw0, kw1);
  irnn_main<<<BATCH / BR, THREADS, 0, stream>>>(x, gb, wf, wdf, hb,
                                                (float*)d_out, ksd0, ksd1);
}